// Round 1
// baseline (10102.074 us; speedup 1.0000x reference)
//
#include <hip/hip_runtime.h>

#define N1 1000000
#define N2 400000
#define N4 150000
#define N8 60000
#define N16 20000

constexpr float BN_EPS = 1e-5f;

__device__ __forceinline__ float lrelu(float x) { return fmaxf(x, 0.1f * x); }

// order-preserving float -> uint encoding; 0u is reserved as "empty" (it would
// only be produced by -NaN, which lrelu outputs never are)
__device__ __forceinline__ unsigned int fenc(float f) {
  unsigned int u = __float_as_uint(f);
  return (u & 0x80000000u) ? ~u : (u | 0x80000000u);
}
__device__ __forceinline__ float fdec(unsigned int u) {
  if (u == 0u) return 0.0f;  // empty segment -> 0 (matches reference isneginf -> 0)
  return (u & 0x80000000u) ? __uint_as_float(u & 0x7fffffffu) : __uint_as_float(~u);
}

// Fold all BatchNorm params into scale/shift once per call.
// Layout in `fold`: enc0 sc[32],sh[32] @0; encR b: sc[32],sh[32] @64+b*64;
// dec i: sc[64],sh[64] @320+i*128.
__global__ void k_fold(const float* g0, const float* be0, const float* m0, const float* v0,
                       const float* gR, const float* beR, const float* mR, const float* vR,
                       const float* gD, const float* beD, const float* mD, const float* vD,
                       float* fold) {
  int t = threadIdx.x;
  if (t < 32) {
    float sc = g0[t] * rsqrtf(v0[t] + BN_EPS);
    fold[t] = sc;
    fold[32 + t] = be0[t] - m0[t] * sc;
  }
  if (t < 128) {
    int b = t >> 5, c = t & 31;
    float sc = gR[b * 32 + c] * rsqrtf(vR[b * 32 + c] + BN_EPS);
    fold[64 + b * 64 + c] = sc;
    fold[64 + b * 64 + 32 + c] = beR[b * 32 + c] - mR[b * 32 + c] * sc;
  }
  for (int i = t; i < 320; i += blockDim.x) {
    int b = i >> 6, c = i & 63;
    float sc = gD[b * 64 + c] * rsqrtf(vD[b * 64 + c] + BN_EPS);
    fold[320 + b * 128 + c] = sc;
    fold[320 + b * 128 + 64 + c] = beD[b * 64 + c] - mD[b * 64 + c] * sc;
  }
}

// encoder block 0: x[9] -> h[32] (lrelu, BN) -> out[64] (lrelu), fused scatter-max
__global__ __launch_bounds__(256) void k_enc0(
    const float* __restrict__ x, const int* __restrict__ idx,
    const float* __restrict__ W1, const float* __restrict__ b1,
    const float* __restrict__ fold,
    const float* __restrict__ W2, const float* __restrict__ b2,
    float* __restrict__ out, unsigned int* seg, int n) {
  int row = blockIdx.x * 256 + threadIdx.x;
  if (row >= n) return;

  float xr[9];
  const float* xp = x + (size_t)row * 9;
#pragma unroll
  for (int k = 0; k < 9; ++k) xr[k] = xp[k];

  float h[32];
#pragma unroll
  for (int j = 0; j < 32; ++j) h[j] = b1[j];
#pragma unroll
  for (int k = 0; k < 9; ++k) {
    float xv = xr[k];
#pragma unroll
    for (int j = 0; j < 32; ++j) h[j] = fmaf(xv, W1[k * 32 + j], h[j]);
  }
#pragma unroll
  for (int j = 0; j < 32; ++j) h[j] = lrelu(h[j]) * fold[j] + fold[32 + j];

  float acc[64];
#pragma unroll
  for (int j = 0; j < 64; ++j) acc[j] = b2[j];
#pragma unroll
  for (int k = 0; k < 32; ++k) {
    float hv = h[k];
#pragma unroll
    for (int j = 0; j < 64; ++j) acc[j] = fmaf(hv, W2[k * 64 + j], acc[j]);
  }

  float* op = out + (size_t)row * 64;
  unsigned int* sp = seg + (size_t)idx[row] * 64;
#pragma unroll
  for (int j = 0; j < 64; ++j) {
    float val = lrelu(acc[j]);
    op[j] = val;
    atomicMax(sp + j, fenc(val));
  }
}

// encoder blocks 1..4: in (encoded segmax) [64] -> h[32] -> out[64], optional scatter-max
__global__ __launch_bounds__(256) void k_encR(
    const unsigned int* __restrict__ xin, const int* __restrict__ idx,
    const float* __restrict__ W1, const float* __restrict__ b1,
    const float* __restrict__ fold,
    const float* __restrict__ W2, const float* __restrict__ b2,
    float* __restrict__ out, unsigned int* seg, int n) {
  int row = blockIdx.x * 256 + threadIdx.x;
  if (row >= n) return;

  float xr[64];
  const uint4* xp = (const uint4*)(xin + (size_t)row * 64);
#pragma unroll
  for (int k = 0; k < 16; ++k) {
    uint4 u = xp[k];
    xr[4 * k + 0] = fdec(u.x);
    xr[4 * k + 1] = fdec(u.y);
    xr[4 * k + 2] = fdec(u.z);
    xr[4 * k + 3] = fdec(u.w);
  }

  float h[32];
#pragma unroll
  for (int j = 0; j < 32; ++j) h[j] = b1[j];
#pragma unroll
  for (int k = 0; k < 64; ++k) {
    float xv = xr[k];
#pragma unroll
    for (int j = 0; j < 32; ++j) h[j] = fmaf(xv, W1[k * 32 + j], h[j]);
  }
#pragma unroll
  for (int j = 0; j < 32; ++j) h[j] = lrelu(h[j]) * fold[j] + fold[32 + j];

  float acc[64];
#pragma unroll
  for (int j = 0; j < 64; ++j) acc[j] = b2[j];
#pragma unroll
  for (int k = 0; k < 32; ++k) {
    float hv = h[k];
#pragma unroll
    for (int j = 0; j < 64; ++j) acc[j] = fmaf(hv, W2[k * 64 + j], acc[j]);
  }

  float* op = out + (size_t)row * 64;
  if (seg) {
    unsigned int* sp = seg + (size_t)idx[row] * 64;
#pragma unroll
    for (int j = 0; j < 64; ++j) {
      float val = lrelu(acc[j]);
      op[j] = val;
      atomicMax(sp + j, fenc(val));
    }
  } else {
#pragma unroll
    for (int j = 0; j < 64; ++j) op[j] = lrelu(acc[j]);
  }
}

// decoder block: skip = lrelu(cur@mlpW+b); h = [skip,last]@decW+b; bn; lrelu.
// Operates IN PLACE on `inout` (each thread reads its row fully before writing).
__global__ __launch_bounds__(256) void k_dec(
    float* inout, const float* lastbuf, const int* __restrict__ idx,
    const float* __restrict__ mlpW, const float* __restrict__ mlpb,
    const float* __restrict__ decW, const float* __restrict__ decb,
    const float* __restrict__ fold, int n) {
  int row = blockIdx.x * 256 + threadIdx.x;
  if (row >= n) return;

  float a[64];
  const float4* cp = (const float4*)(inout + (size_t)row * 64);
#pragma unroll
  for (int k = 0; k < 16; ++k) {
    float4 t = cp[k];
    a[4 * k + 0] = t.x; a[4 * k + 1] = t.y; a[4 * k + 2] = t.z; a[4 * k + 3] = t.w;
  }

  float b[64];
#pragma unroll
  for (int j = 0; j < 64; ++j) b[j] = mlpb[j];
#pragma unroll
  for (int k = 0; k < 64; ++k) {
    float av = a[k];
#pragma unroll
    for (int j = 0; j < 64; ++j) b[j] = fmaf(av, mlpW[k * 64 + j], b[j]);
  }
#pragma unroll
  for (int j = 0; j < 64; ++j) b[j] = lrelu(b[j]);

  float acc[64];
#pragma unroll
  for (int j = 0; j < 64; ++j) acc[j] = decb[j];
#pragma unroll
  for (int k = 0; k < 64; ++k) {
    float sv = b[k];
#pragma unroll
    for (int j = 0; j < 64; ++j) acc[j] = fmaf(sv, decW[k * 64 + j], acc[j]);
  }

  int lrow = idx ? idx[row] : row;
  const float4* lp = (const float4*)(lastbuf + (size_t)lrow * 64);
#pragma unroll
  for (int k = 0; k < 16; ++k) {
    float4 t = lp[k];
    a[4 * k + 0] = t.x; a[4 * k + 1] = t.y; a[4 * k + 2] = t.z; a[4 * k + 3] = t.w;
  }
#pragma unroll
  for (int k = 0; k < 64; ++k) {
    float lv = a[k];
#pragma unroll
    for (int j = 0; j < 64; ++j) acc[j] = fmaf(lv, decW[(64 + k) * 64 + j], acc[j]);
  }

  float4* opv = (float4*)(inout + (size_t)row * 64);
#pragma unroll
  for (int k = 0; k < 16; ++k) {
    float4 t;
    t.x = lrelu(acc[4 * k + 0] * fold[4 * k + 0] + fold[64 + 4 * k + 0]);
    t.y = lrelu(acc[4 * k + 1] * fold[4 * k + 1] + fold[64 + 4 * k + 1]);
    t.z = lrelu(acc[4 * k + 2] * fold[4 * k + 2] + fold[64 + 4 * k + 2]);
    t.w = lrelu(acc[4 * k + 3] * fold[4 * k + 3] + fold[64 + 4 * k + 3]);
    opv[k] = t;
  }
}

extern "C" void kernel_launch(void* const* d_in, const int* in_sizes, int n_in,
                              void* d_out, int out_size, void* d_ws, size_t ws_size,
                              hipStream_t stream) {
  const float* pt   = (const float*)d_in[0];
  const int* inv2   = (const int*)d_in[1];
  const int* inv4   = (const int*)d_in[2];
  const int* inv8   = (const int*)d_in[3];
  const int* inv16  = (const int*)d_in[4];
  const float* e0W1 = (const float*)d_in[5];
  const float* e0b1 = (const float*)d_in[6];
  const float* e0g  = (const float*)d_in[7];
  const float* e0be = (const float*)d_in[8];
  const float* e0m  = (const float*)d_in[9];
  const float* e0v  = (const float*)d_in[10];
  const float* e0W2 = (const float*)d_in[11];
  const float* e0b2 = (const float*)d_in[12];
  const float* eRW1 = (const float*)d_in[13];
  const float* eRb1 = (const float*)d_in[14];
  const float* eRg  = (const float*)d_in[15];
  const float* eRbe = (const float*)d_in[16];
  const float* eRm  = (const float*)d_in[17];
  const float* eRv  = (const float*)d_in[18];
  const float* eRW2 = (const float*)d_in[19];
  const float* eRb2 = (const float*)d_in[20];
  const float* mlpW = (const float*)d_in[21];
  const float* mlpb = (const float*)d_in[22];
  const float* decW = (const float*)d_in[23];
  const float* decb = (const float*)d_in[24];
  const float* decg = (const float*)d_in[25];
  const float* decbe= (const float*)d_in[26];
  const float* decm = (const float*)d_in[27];
  const float* decv = (const float*)d_in[28];

  float* s1 = (float*)d_out;
  float* s2 = s1 + (size_t)N1 * 64;
  float* s3 = s2 + (size_t)N2 * 64;
  float* s4 = s3 + (size_t)N4 * 64;
  float* s5 = s4 + (size_t)N8 * 64;

  unsigned char* ws = (unsigned char*)d_ws;
  unsigned int* oA = (unsigned int*)ws;                               // up to N2*64
  unsigned int* oB = (unsigned int*)(ws + (size_t)N2 * 64 * 4);       // up to N4*64
  float* fold      = (float*)(ws + (size_t)(N2 + N4) * 64 * 4);       // 960 floats

  k_fold<<<1, 320, 0, stream>>>(e0g, e0be, e0m, e0v, eRg, eRbe, eRm, eRv,
                                decg, decbe, decm, decv, fold);
  hipMemsetAsync(oA, 0, (size_t)N2 * 64 * 4, stream);
  hipMemsetAsync(oB, 0, (size_t)N4 * 64 * 4, stream);

  k_enc0<<<(N1 + 255) / 256, 256, 0, stream>>>(pt, inv2, e0W1, e0b1, fold, e0W2, e0b2,
                                               s1, oA, N1);
  k_encR<<<(N2 + 255) / 256, 256, 0, stream>>>(oA, inv4, eRW1 + 0 * 2048, eRb1 + 0 * 32,
                                               fold + 64 + 0 * 64, eRW2 + 0 * 2048,
                                               eRb2 + 0 * 64, s2, oB, N2);
  hipMemsetAsync(oA, 0, (size_t)N8 * 64 * 4, stream);
  k_encR<<<(N4 + 255) / 256, 256, 0, stream>>>(oB, inv8, eRW1 + 1 * 2048, eRb1 + 1 * 32,
                                               fold + 64 + 1 * 64, eRW2 + 1 * 2048,
                                               eRb2 + 1 * 64, s3, oA, N4);
  hipMemsetAsync(oB, 0, (size_t)N16 * 64 * 4, stream);
  k_encR<<<(N8 + 255) / 256, 256, 0, stream>>>(oA, inv16, eRW1 + 2 * 2048, eRb1 + 2 * 32,
                                               fold + 64 + 2 * 64, eRW2 + 2 * 2048,
                                               eRb2 + 2 * 64, s4, oB, N8);
  k_encR<<<(N16 + 255) / 256, 256, 0, stream>>>(oB, nullptr, eRW1 + 3 * 2048, eRb1 + 3 * 32,
                                                fold + 64 + 3 * 64, eRW2 + 3 * 2048,
                                                eRb2 + 3 * 64, s5, nullptr, N16);

  k_dec<<<(N16 + 255) / 256, 256, 0, stream>>>(s5, s5, nullptr, mlpW + 0 * 4096, mlpb + 0 * 64,
                                               decW + 0 * 8192, decb + 0 * 64,
                                               fold + 320 + 0 * 128, N16);
  k_dec<<<(N8 + 255) / 256, 256, 0, stream>>>(s4, s5, inv16, mlpW + 1 * 4096, mlpb + 1 * 64,
                                              decW + 1 * 8192, decb + 1 * 64,
                                              fold + 320 + 1 * 128, N8);
  k_dec<<<(N4 + 255) / 256, 256, 0, stream>>>(s3, s4, inv8, mlpW + 2 * 4096, mlpb + 2 * 64,
                                              decW + 2 * 8192, decb + 2 * 64,
                                              fold + 320 + 2 * 128, N4);
  k_dec<<<(N2 + 255) / 256, 256, 0, stream>>>(s2, s3, inv4, mlpW + 3 * 4096, mlpb + 3 * 64,
                                              decW + 3 * 8192, decb + 3 * 64,
                                              fold + 320 + 3 * 128, N2);
  k_dec<<<(N1 + 255) / 256, 256, 0, stream>>>(s1, s2, inv2, mlpW + 4 * 4096, mlpb + 4 * 64,
                                              decW + 4 * 8192, decb + 4 * 64,
                                              fold + 320 + 4 * 128, N1);
}

// Round 2
// 6058.038 us; speedup vs baseline: 1.6675x; 1.6675x over previous
//
#include <hip/hip_runtime.h>

#define N1 1000000
#define N2 400000
#define N4 150000
#define N8 60000
#define N16 20000

constexpr float BN_EPS = 1e-5f;

__device__ __forceinline__ float lrelu(float x) { return fmaxf(x, 0.1f * x); }

// order-preserving float -> uint encoding; 0u is reserved as "empty"
__device__ __forceinline__ unsigned int fenc(float f) {
  unsigned int u = __float_as_uint(f);
  return (u & 0x80000000u) ? ~u : (u | 0x80000000u);
}
__device__ __forceinline__ float fdec(unsigned int u) {
  if (u == 0u) return 0.0f;  // empty segment -> 0 (matches reference)
  return (u & 0x80000000u) ? __uint_as_float(u & 0x7fffffffu) : __uint_as_float(~u);
}

// Fold all BatchNorm params into scale/shift once per call.
// fold: enc0 sc[32],sh[32] @0; encR b: sc[32],sh[32] @64+b*64; dec i: sc[64],sh[64] @320+i*128.
__global__ void k_fold(const float* g0, const float* be0, const float* m0, const float* v0,
                       const float* gR, const float* beR, const float* mR, const float* vR,
                       const float* gD, const float* beD, const float* mD, const float* vD,
                       float* fold) {
  int t = threadIdx.x;
  if (t < 32) {
    float sc = g0[t] * rsqrtf(v0[t] + BN_EPS);
    fold[t] = sc;
    fold[32 + t] = be0[t] - m0[t] * sc;
  }
  if (t < 128) {
    int b = t >> 5, c = t & 31;
    float sc = gR[b * 32 + c] * rsqrtf(vR[b * 32 + c] + BN_EPS);
    fold[64 + b * 64 + c] = sc;
    fold[64 + b * 64 + 32 + c] = beR[b * 32 + c] - mR[b * 32 + c] * sc;
  }
  for (int i = t; i < 320; i += blockDim.x) {
    int b = i >> 6, c = i & 63;
    float sc = gD[b * 64 + c] * rsqrtf(vD[b * 64 + c] + BN_EPS);
    fold[320 + b * 128 + c] = sc;
    fold[320 + b * 128 + 64 + c] = beD[b * 64 + c] - mD[b * 64 + c] * sc;
  }
}

// encoder block 0: x[9] -> h[32] (lrelu, BN) -> out[64] (lrelu), fused scatter-max
// live peak ~ h[32]+acc[64] = 96 -> fits 128 VGPR (4 waves/EU)
__global__ __launch_bounds__(256, 4) void k_enc0(
    const float* __restrict__ x, const int* __restrict__ idx,
    const float* __restrict__ W1, const float* __restrict__ b1,
    const float* __restrict__ fold,
    const float* __restrict__ W2, const float* __restrict__ b2,
    float* __restrict__ out, unsigned int* seg, int n) {
  int row = blockIdx.x * 256 + threadIdx.x;
  if (row >= n) return;

  float xr[9];
  const float* xp = x + (size_t)row * 9;
#pragma unroll
  for (int k = 0; k < 9; ++k) xr[k] = xp[k];

  float h[32];
#pragma unroll
  for (int j = 0; j < 32; ++j) h[j] = b1[j];
#pragma unroll
  for (int k = 0; k < 9; ++k) {
    float xv = xr[k];
#pragma unroll
    for (int j = 0; j < 32; ++j) h[j] = fmaf(xv, W1[k * 32 + j], h[j]);
  }
#pragma unroll
  for (int j = 0; j < 32; ++j) h[j] = lrelu(h[j]) * fold[j] + fold[32 + j];

  float acc[64];
#pragma unroll
  for (int j = 0; j < 64; ++j) acc[j] = b2[j];
#pragma unroll
  for (int k = 0; k < 32; ++k) {
    float hv = h[k];
#pragma unroll
    for (int j = 0; j < 64; ++j) acc[j] = fmaf(hv, W2[k * 64 + j], acc[j]);
  }

  float* op = out + (size_t)row * 64;
  unsigned int* sp = seg + (size_t)idx[row] * 64;
#pragma unroll
  for (int j = 0; j < 64; ++j) {
    float val = lrelu(acc[j]);
    op[j] = val;
    atomicMax(sp + j, fenc(val));
  }
}

// encoder blocks 1..4: live peak ~ xr[64]+h[32] = 96 (+temps) -> 3 waves/EU budget (<=170)
__global__ __launch_bounds__(256, 3) void k_encR(
    const unsigned int* __restrict__ xin, const int* __restrict__ idx,
    const float* __restrict__ W1, const float* __restrict__ b1,
    const float* __restrict__ fold,
    const float* __restrict__ W2, const float* __restrict__ b2,
    float* __restrict__ out, unsigned int* seg, int n) {
  int row = blockIdx.x * 256 + threadIdx.x;
  if (row >= n) return;

  float xr[64];
  const uint4* xp = (const uint4*)(xin + (size_t)row * 64);
#pragma unroll
  for (int k = 0; k < 16; ++k) {
    uint4 u = xp[k];
    xr[4 * k + 0] = fdec(u.x);
    xr[4 * k + 1] = fdec(u.y);
    xr[4 * k + 2] = fdec(u.z);
    xr[4 * k + 3] = fdec(u.w);
  }

  float h[32];
#pragma unroll
  for (int j = 0; j < 32; ++j) h[j] = b1[j];
#pragma unroll
  for (int k = 0; k < 64; ++k) {
    float xv = xr[k];
#pragma unroll
    for (int j = 0; j < 32; ++j) h[j] = fmaf(xv, W1[k * 32 + j], h[j]);
  }
#pragma unroll
  for (int j = 0; j < 32; ++j) h[j] = lrelu(h[j]) * fold[j] + fold[32 + j];

  float acc[64];
#pragma unroll
  for (int j = 0; j < 64; ++j) acc[j] = b2[j];
#pragma unroll
  for (int k = 0; k < 32; ++k) {
    float hv = h[k];
#pragma unroll
    for (int j = 0; j < 64; ++j) acc[j] = fmaf(hv, W2[k * 64 + j], acc[j]);
  }

  float* op = out + (size_t)row * 64;
  if (seg) {
    unsigned int* sp = seg + (size_t)idx[row] * 64;
#pragma unroll
    for (int j = 0; j < 64; ++j) {
      float val = lrelu(acc[j]);
      op[j] = val;
      atomicMax(sp + j, fenc(val));
    }
  } else {
#pragma unroll
    for (int j = 0; j < 64; ++j) op[j] = lrelu(acc[j]);
  }
}

// decoder block, spill-free restructure:
//   out = decb + last @ decW[64:128]          (live: last[64]+out[64] = 128)
//   then per 8-ch chunk c of skip:
//     sk[8] = lrelu(cur @ mlpW[:, c])         (live: cur[64]+out[64]+sk[8] = 136)
//     out  += sk @ decW[c*8 : c*8+8]
//   bn + lrelu, store in place.
// __launch_bounds__(256,2): 256-VGPR budget -> no spills.
__global__ __launch_bounds__(256, 2) void k_dec(
    float* inout, const float* lastbuf, const int* __restrict__ idx,
    const float* __restrict__ mlpW, const float* __restrict__ mlpb,
    const float* __restrict__ decW, const float* __restrict__ decb,
    const float* __restrict__ fold, int n) {
  int row = blockIdx.x * 256 + threadIdx.x;
  if (row >= n) return;
  int lrow = idx ? idx[row] : row;

  float out[64];
#pragma unroll
  for (int j = 0; j < 64; ++j) out[j] = decb[j];

  float xr[64];
  // ---- last contribution: decW rows 64..127 ----
  {
    const float4* lp = (const float4*)(lastbuf + (size_t)lrow * 64);
#pragma unroll
    for (int k = 0; k < 16; ++k) {
      float4 t = lp[k];
      xr[4 * k + 0] = t.x; xr[4 * k + 1] = t.y; xr[4 * k + 2] = t.z; xr[4 * k + 3] = t.w;
    }
  }
#pragma unroll
  for (int k = 0; k < 64; ++k) {
    float lv = xr[k];
#pragma unroll
    for (int j = 0; j < 64; ++j) out[j] = fmaf(lv, decW[(64 + k) * 64 + j], out[j]);
  }

  // ---- cur row ----
  {
    const float4* cp = (const float4*)(inout + (size_t)row * 64);
#pragma unroll
    for (int k = 0; k < 16; ++k) {
      float4 t = cp[k];
      xr[4 * k + 0] = t.x; xr[4 * k + 1] = t.y; xr[4 * k + 2] = t.z; xr[4 * k + 3] = t.w;
    }
  }

  // ---- skip MLP in 8-channel chunks, accumulated immediately ----
#pragma unroll
  for (int c = 0; c < 8; ++c) {
    float sk[8];
#pragma unroll
    for (int j = 0; j < 8; ++j) sk[j] = mlpb[c * 8 + j];
#pragma unroll
    for (int k = 0; k < 64; ++k) {
      float cv = xr[k];
#pragma unroll
      for (int j = 0; j < 8; ++j) sk[j] = fmaf(cv, mlpW[k * 64 + c * 8 + j], sk[j]);
    }
#pragma unroll
    for (int j = 0; j < 8; ++j) sk[j] = lrelu(sk[j]);
#pragma unroll
    for (int k2 = 0; k2 < 8; ++k2) {
      float sv = sk[k2];
#pragma unroll
      for (int j = 0; j < 64; ++j) out[j] = fmaf(sv, decW[(c * 8 + k2) * 64 + j], out[j]);
    }
  }

  float4* opv = (float4*)(inout + (size_t)row * 64);
#pragma unroll
  for (int k = 0; k < 16; ++k) {
    float4 t;
    t.x = lrelu(out[4 * k + 0] * fold[4 * k + 0] + fold[64 + 4 * k + 0]);
    t.y = lrelu(out[4 * k + 1] * fold[4 * k + 1] + fold[64 + 4 * k + 1]);
    t.z = lrelu(out[4 * k + 2] * fold[4 * k + 2] + fold[64 + 4 * k + 2]);
    t.w = lrelu(out[4 * k + 3] * fold[4 * k + 3] + fold[64 + 4 * k + 3]);
    opv[k] = t;
  }
}

extern "C" void kernel_launch(void* const* d_in, const int* in_sizes, int n_in,
                              void* d_out, int out_size, void* d_ws, size_t ws_size,
                              hipStream_t stream) {
  const float* pt   = (const float*)d_in[0];
  const int* inv2   = (const int*)d_in[1];
  const int* inv4   = (const int*)d_in[2];
  const int* inv8   = (const int*)d_in[3];
  const int* inv16  = (const int*)d_in[4];
  const float* e0W1 = (const float*)d_in[5];
  const float* e0b1 = (const float*)d_in[6];
  const float* e0g  = (const float*)d_in[7];
  const float* e0be = (const float*)d_in[8];
  const float* e0m  = (const float*)d_in[9];
  const float* e0v  = (const float*)d_in[10];
  const float* e0W2 = (const float*)d_in[11];
  const float* e0b2 = (const float*)d_in[12];
  const float* eRW1 = (const float*)d_in[13];
  const float* eRb1 = (const float*)d_in[14];
  const float* eRg  = (const float*)d_in[15];
  const float* eRbe = (const float*)d_in[16];
  const float* eRm  = (const float*)d_in[17];
  const float* eRv  = (const float*)d_in[18];
  const float* eRW2 = (const float*)d_in[19];
  const float* eRb2 = (const float*)d_in[20];
  const float* mlpW = (const float*)d_in[21];
  const float* mlpb = (const float*)d_in[22];
  const float* decW = (const float*)d_in[23];
  const float* decb = (const float*)d_in[24];
  const float* decg = (const float*)d_in[25];
  const float* decbe= (const float*)d_in[26];
  const float* decm = (const float*)d_in[27];
  const float* decv = (const float*)d_in[28];

  float* s1 = (float*)d_out;
  float* s2 = s1 + (size_t)N1 * 64;
  float* s3 = s2 + (size_t)N2 * 64;
  float* s4 = s3 + (size_t)N4 * 64;
  float* s5 = s4 + (size_t)N8 * 64;

  unsigned char* ws = (unsigned char*)d_ws;
  unsigned int* oA = (unsigned int*)ws;                               // up to N2*64
  unsigned int* oB = (unsigned int*)(ws + (size_t)N2 * 64 * 4);       // up to N4*64
  float* fold      = (float*)(ws + (size_t)(N2 + N4) * 64 * 4);       // 960 floats

  k_fold<<<1, 320, 0, stream>>>(e0g, e0be, e0m, e0v, eRg, eRbe, eRm, eRv,
                                decg, decbe, decm, decv, fold);
  hipMemsetAsync(oA, 0, (size_t)N2 * 64 * 4, stream);
  hipMemsetAsync(oB, 0, (size_t)N4 * 64 * 4, stream);

  k_enc0<<<(N1 + 255) / 256, 256, 0, stream>>>(pt, inv2, e0W1, e0b1, fold, e0W2, e0b2,
                                               s1, oA, N1);
  k_encR<<<(N2 + 255) / 256, 256, 0, stream>>>(oA, inv4, eRW1 + 0 * 2048, eRb1 + 0 * 32,
                                               fold + 64 + 0 * 64, eRW2 + 0 * 2048,
                                               eRb2 + 0 * 64, s2, oB, N2);
  hipMemsetAsync(oA, 0, (size_t)N8 * 64 * 4, stream);
  k_encR<<<(N4 + 255) / 256, 256, 0, stream>>>(oB, inv8, eRW1 + 1 * 2048, eRb1 + 1 * 32,
                                               fold + 64 + 1 * 64, eRW2 + 1 * 2048,
                                               eRb2 + 1 * 64, s3, oA, N4);
  hipMemsetAsync(oB, 0, (size_t)N16 * 64 * 4, stream);
  k_encR<<<(N8 + 255) / 256, 256, 0, stream>>>(oA, inv16, eRW1 + 2 * 2048, eRb1 + 2 * 32,
                                               fold + 64 + 2 * 64, eRW2 + 2 * 2048,
                                               eRb2 + 2 * 64, s4, oB, N8);
  k_encR<<<(N16 + 255) / 256, 256, 0, stream>>>(oB, nullptr, eRW1 + 3 * 2048, eRb1 + 3 * 32,
                                                fold + 64 + 3 * 64, eRW2 + 3 * 2048,
                                                eRb2 + 3 * 64, s5, nullptr, N16);

  k_dec<<<(N16 + 255) / 256, 256, 0, stream>>>(s5, s5, nullptr, mlpW + 0 * 4096, mlpb + 0 * 64,
                                               decW + 0 * 8192, decb + 0 * 64,
                                               fold + 320 + 0 * 128, N16);
  k_dec<<<(N8 + 255) / 256, 256, 0, stream>>>(s4, s5, inv16, mlpW + 1 * 4096, mlpb + 1 * 64,
                                              decW + 1 * 8192, decb + 1 * 64,
                                              fold + 320 + 1 * 128, N8);
  k_dec<<<(N4 + 255) / 256, 256, 0, stream>>>(s3, s4, inv8, mlpW + 2 * 4096, mlpb + 2 * 64,
                                              decW + 2 * 8192, decb + 2 * 64,
                                              fold + 320 + 2 * 128, N4);
  k_dec<<<(N2 + 255) / 256, 256, 0, stream>>>(s2, s3, inv4, mlpW + 3 * 4096, mlpb + 3 * 64,
                                              decW + 3 * 8192, decb + 3 * 64,
                                              fold + 320 + 3 * 128, N2);
  k_dec<<<(N1 + 255) / 256, 256, 0, stream>>>(s1, s2, inv2, mlpW + 4 * 4096, mlpb + 4 * 64,
                                              decW + 4 * 8192, decb + 4 * 64,
                                              fold + 320 + 4 * 128, N1);
}

// Round 3
// 2329.803 us; speedup vs baseline: 4.3360x; 2.6002x over previous
//
#include <hip/hip_runtime.h>

#define N1 1000000
#define N2 400000
#define N4 150000
#define N8 60000
#define N16 20000

constexpr float BN_EPS = 1e-5f;

__device__ __forceinline__ float lrelu(float x) { return fmaxf(x, 0.1f * x); }

// Fold all BatchNorm params into scale/shift once per call.
// fold: enc0 sc[32],sh[32] @0; encR b: sc[32],sh[32] @64+b*64; dec i: sc[64],sh[64] @320+i*128.
__global__ void k_fold(const float* g0, const float* be0, const float* m0, const float* v0,
                       const float* gR, const float* beR, const float* mR, const float* vR,
                       const float* gD, const float* beD, const float* mD, const float* vD,
                       float* fold) {
  int t = threadIdx.x;
  if (t < 32) {
    float sc = g0[t] * rsqrtf(v0[t] + BN_EPS);
    fold[t] = sc;
    fold[32 + t] = be0[t] - m0[t] * sc;
  }
  if (t < 128) {
    int b = t >> 5, c = t & 31;
    float sc = gR[b * 32 + c] * rsqrtf(vR[b * 32 + c] + BN_EPS);
    fold[64 + b * 64 + c] = sc;
    fold[64 + b * 64 + 32 + c] = beR[b * 32 + c] - mR[b * 32 + c] * sc;
  }
  for (int i = t; i < 320; i += blockDim.x) {
    int b = i >> 6, c = i & 63;
    float sc = gD[b * 64 + c] * rsqrtf(vD[b * 64 + c] + BN_EPS);
    fold[320 + b * 128 + c] = sc;
    fold[320 + b * 128 + 64 + c] = beD[b * 64 + c] - mD[b * 64 + c] * sc;
  }
}

// Build per-segment linked lists: next[i] = old head[idx[i]]; head[idx[i]] = i.
// head must be pre-set to -1 (memset 0xFF). One 4B atomic per row.
__global__ __launch_bounds__(256) void k_fill(const int* __restrict__ idx,
                                              int* head, int* nxt, int n) {
  int i = blockIdx.x * 256 + threadIdx.x;
  if (i < n) nxt[i] = atomicExch(&head[idx[i]], i);
}

// Segment max by chained gather. One wave (64 threads) per segment, one thread
// per channel. head/nxt loads are wave-uniform (broadcast); row reads are
// coalesced 256B bursts. Empty chain -> 0 (matches reference).
__global__ __launch_bounds__(256) void k_gmax(
    const float* __restrict__ src, const int* __restrict__ head,
    const int* __restrict__ nxt, float* __restrict__ dst, int nseg) {
  int t = blockIdx.x * 256 + threadIdx.x;
  int seg = t >> 6, ch = t & 63;
  if (seg >= nseg) return;
  float m = -INFINITY;
  for (int p = head[seg]; p >= 0; p = nxt[p])
    m = fmaxf(m, src[(size_t)p * 64 + ch]);
  dst[(size_t)seg * 64 + ch] = (m == -INFINITY) ? 0.0f : m;
}

// encoder block 0: x[9] -> h[32] (lrelu, BN) -> out[64] (lrelu)
__global__ __launch_bounds__(256, 4) void k_enc0(
    const float* __restrict__ x,
    const float* __restrict__ W1, const float* __restrict__ b1,
    const float* __restrict__ fold,
    const float* __restrict__ W2, const float* __restrict__ b2,
    float* __restrict__ out, int n) {
  int row = blockIdx.x * 256 + threadIdx.x;
  if (row >= n) return;

  float xr[9];
  const float* xp = x + (size_t)row * 9;
#pragma unroll
  for (int k = 0; k < 9; ++k) xr[k] = xp[k];

  float h[32];
#pragma unroll
  for (int j = 0; j < 32; ++j) h[j] = b1[j];
#pragma unroll
  for (int k = 0; k < 9; ++k) {
    float xv = xr[k];
#pragma unroll
    for (int j = 0; j < 32; ++j) h[j] = fmaf(xv, W1[k * 32 + j], h[j]);
  }
#pragma unroll
  for (int j = 0; j < 32; ++j) h[j] = lrelu(h[j]) * fold[j] + fold[32 + j];

  float acc[64];
#pragma unroll
  for (int j = 0; j < 64; ++j) acc[j] = b2[j];
#pragma unroll
  for (int k = 0; k < 32; ++k) {
    float hv = h[k];
#pragma unroll
    for (int j = 0; j < 64; ++j) acc[j] = fmaf(hv, W2[k * 64 + j], acc[j]);
  }

  float4* opv = (float4*)(out + (size_t)row * 64);
#pragma unroll
  for (int k = 0; k < 16; ++k) {
    float4 t;
    t.x = lrelu(acc[4 * k + 0]); t.y = lrelu(acc[4 * k + 1]);
    t.z = lrelu(acc[4 * k + 2]); t.w = lrelu(acc[4 * k + 3]);
    opv[k] = t;
  }
}

// encoder blocks 1..4: in[64] -> h[32] (lrelu, BN) -> out[64] (lrelu)
__global__ __launch_bounds__(256, 3) void k_encR(
    const float* __restrict__ xin,
    const float* __restrict__ W1, const float* __restrict__ b1,
    const float* __restrict__ fold,
    const float* __restrict__ W2, const float* __restrict__ b2,
    float* __restrict__ out, int n) {
  int row = blockIdx.x * 256 + threadIdx.x;
  if (row >= n) return;

  float xr[64];
  const float4* xp = (const float4*)(xin + (size_t)row * 64);
#pragma unroll
  for (int k = 0; k < 16; ++k) {
    float4 u = xp[k];
    xr[4 * k + 0] = u.x; xr[4 * k + 1] = u.y; xr[4 * k + 2] = u.z; xr[4 * k + 3] = u.w;
  }

  float h[32];
#pragma unroll
  for (int j = 0; j < 32; ++j) h[j] = b1[j];
#pragma unroll
  for (int k = 0; k < 64; ++k) {
    float xv = xr[k];
#pragma unroll
    for (int j = 0; j < 32; ++j) h[j] = fmaf(xv, W1[k * 32 + j], h[j]);
  }
#pragma unroll
  for (int j = 0; j < 32; ++j) h[j] = lrelu(h[j]) * fold[j] + fold[32 + j];

  float acc[64];
#pragma unroll
  for (int j = 0; j < 64; ++j) acc[j] = b2[j];
#pragma unroll
  for (int k = 0; k < 32; ++k) {
    float hv = h[k];
#pragma unroll
    for (int j = 0; j < 64; ++j) acc[j] = fmaf(hv, W2[k * 64 + j], acc[j]);
  }

  float4* opv = (float4*)(out + (size_t)row * 64);
#pragma unroll
  for (int k = 0; k < 16; ++k) {
    float4 t;
    t.x = lrelu(acc[4 * k + 0]); t.y = lrelu(acc[4 * k + 1]);
    t.z = lrelu(acc[4 * k + 2]); t.w = lrelu(acc[4 * k + 3]);
    opv[k] = t;
  }
}

// decoder block (spill-free chunked form), in place on `inout`.
__global__ __launch_bounds__(256, 2) void k_dec(
    float* inout, const float* lastbuf, const int* __restrict__ idx,
    const float* __restrict__ mlpW, const float* __restrict__ mlpb,
    const float* __restrict__ decW, const float* __restrict__ decb,
    const float* __restrict__ fold, int n) {
  int row = blockIdx.x * 256 + threadIdx.x;
  if (row >= n) return;
  int lrow = idx ? idx[row] : row;

  float out[64];
#pragma unroll
  for (int j = 0; j < 64; ++j) out[j] = decb[j];

  float xr[64];
  // ---- last contribution: decW rows 64..127 ----
  {
    const float4* lp = (const float4*)(lastbuf + (size_t)lrow * 64);
#pragma unroll
    for (int k = 0; k < 16; ++k) {
      float4 t = lp[k];
      xr[4 * k + 0] = t.x; xr[4 * k + 1] = t.y; xr[4 * k + 2] = t.z; xr[4 * k + 3] = t.w;
    }
  }
#pragma unroll
  for (int k = 0; k < 64; ++k) {
    float lv = xr[k];
#pragma unroll
    for (int j = 0; j < 64; ++j) out[j] = fmaf(lv, decW[(64 + k) * 64 + j], out[j]);
  }

  // ---- cur row ----
  {
    const float4* cp = (const float4*)(inout + (size_t)row * 64);
#pragma unroll
    for (int k = 0; k < 16; ++k) {
      float4 t = cp[k];
      xr[4 * k + 0] = t.x; xr[4 * k + 1] = t.y; xr[4 * k + 2] = t.z; xr[4 * k + 3] = t.w;
    }
  }

  // ---- skip MLP in 8-channel chunks, accumulated immediately ----
#pragma unroll
  for (int c = 0; c < 8; ++c) {
    float sk[8];
#pragma unroll
    for (int j = 0; j < 8; ++j) sk[j] = mlpb[c * 8 + j];
#pragma unroll
    for (int k = 0; k < 64; ++k) {
      float cv = xr[k];
#pragma unroll
      for (int j = 0; j < 8; ++j) sk[j] = fmaf(cv, mlpW[k * 64 + c * 8 + j], sk[j]);
    }
#pragma unroll
    for (int j = 0; j < 8; ++j) sk[j] = lrelu(sk[j]);
#pragma unroll
    for (int k2 = 0; k2 < 8; ++k2) {
      float sv = sk[k2];
#pragma unroll
      for (int j = 0; j < 64; ++j) out[j] = fmaf(sv, decW[(c * 8 + k2) * 64 + j], out[j]);
    }
  }

  float4* opv = (float4*)(inout + (size_t)row * 64);
#pragma unroll
  for (int k = 0; k < 16; ++k) {
    float4 t;
    t.x = lrelu(out[4 * k + 0] * fold[4 * k + 0] + fold[64 + 4 * k + 0]);
    t.y = lrelu(out[4 * k + 1] * fold[4 * k + 1] + fold[64 + 4 * k + 1]);
    t.z = lrelu(out[4 * k + 2] * fold[4 * k + 2] + fold[64 + 4 * k + 2]);
    t.w = lrelu(out[4 * k + 3] * fold[4 * k + 3] + fold[64 + 4 * k + 3]);
    opv[k] = t;
  }
}

extern "C" void kernel_launch(void* const* d_in, const int* in_sizes, int n_in,
                              void* d_out, int out_size, void* d_ws, size_t ws_size,
                              hipStream_t stream) {
  const float* pt   = (const float*)d_in[0];
  const int* inv2   = (const int*)d_in[1];
  const int* inv4   = (const int*)d_in[2];
  const int* inv8   = (const int*)d_in[3];
  const int* inv16  = (const int*)d_in[4];
  const float* e0W1 = (const float*)d_in[5];
  const float* e0b1 = (const float*)d_in[6];
  const float* e0g  = (const float*)d_in[7];
  const float* e0be = (const float*)d_in[8];
  const float* e0m  = (const float*)d_in[9];
  const float* e0v  = (const float*)d_in[10];
  const float* e0W2 = (const float*)d_in[11];
  const float* e0b2 = (const float*)d_in[12];
  const float* eRW1 = (const float*)d_in[13];
  const float* eRb1 = (const float*)d_in[14];
  const float* eRg  = (const float*)d_in[15];
  const float* eRbe = (const float*)d_in[16];
  const float* eRm  = (const float*)d_in[17];
  const float* eRv  = (const float*)d_in[18];
  const float* eRW2 = (const float*)d_in[19];
  const float* eRb2 = (const float*)d_in[20];
  const float* mlpW = (const float*)d_in[21];
  const float* mlpb = (const float*)d_in[22];
  const float* decW = (const float*)d_in[23];
  const float* decb = (const float*)d_in[24];
  const float* decg = (const float*)d_in[25];
  const float* decbe= (const float*)d_in[26];
  const float* decm = (const float*)d_in[27];
  const float* decv = (const float*)d_in[28];

  float* s1 = (float*)d_out;
  float* s2 = s1 + (size_t)N1 * 64;
  float* s3 = s2 + (size_t)N2 * 64;
  float* s4 = s3 + (size_t)N4 * 64;
  float* s5 = s4 + (size_t)N8 * 64;

  // workspace: fold | oA (N2*64 f) | oB (N4*64 f) | head (N2 i) | nxt (N1 i)
  float* fold = (float*)d_ws;
  float* oA   = fold + 1024;
  float* oB   = oA + (size_t)N2 * 64;
  int* head   = (int*)(oB + (size_t)N4 * 64);
  int* nxt    = head + N2;

  k_fold<<<1, 320, 0, stream>>>(e0g, e0be, e0m, e0v, eRg, eRbe, eRm, eRv,
                                decg, decbe, decm, decv, fold);

  // ---- level 1: enc0 on N1, pool -> oA [N2] ----
  hipMemsetAsync(head, 0xFF, (size_t)N2 * 4, stream);
  k_fill<<<(N1 + 255) / 256, 256, 0, stream>>>(inv2, head, nxt, N1);
  k_enc0<<<(N1 + 255) / 256, 256, 0, stream>>>(pt, e0W1, e0b1, fold, e0W2, e0b2, s1, N1);
  k_gmax<<<((size_t)N2 * 64 + 255) / 256, 256, 0, stream>>>(s1, head, nxt, oA, N2);

  // ---- level 2: encR[0] on N2, pool -> oB [N4] ----
  hipMemsetAsync(head, 0xFF, (size_t)N4 * 4, stream);
  k_fill<<<(N2 + 255) / 256, 256, 0, stream>>>(inv4, head, nxt, N2);
  k_encR<<<(N2 + 255) / 256, 256, 0, stream>>>(oA, eRW1 + 0 * 2048, eRb1 + 0 * 32,
                                               fold + 64 + 0 * 64, eRW2 + 0 * 2048,
                                               eRb2 + 0 * 64, s2, N2);
  k_gmax<<<((size_t)N4 * 64 + 255) / 256, 256, 0, stream>>>(s2, head, nxt, oB, N4);

  // ---- level 3: encR[1] on N4, pool -> oA [N8] ----
  hipMemsetAsync(head, 0xFF, (size_t)N8 * 4, stream);
  k_fill<<<(N4 + 255) / 256, 256, 0, stream>>>(inv8, head, nxt, N4);
  k_encR<<<(N4 + 255) / 256, 256, 0, stream>>>(oB, eRW1 + 1 * 2048, eRb1 + 1 * 32,
                                               fold + 64 + 1 * 64, eRW2 + 1 * 2048,
                                               eRb2 + 1 * 64, s3, N4);
  k_gmax<<<((size_t)N8 * 64 + 255) / 256, 256, 0, stream>>>(s3, head, nxt, oA, N8);

  // ---- level 4: encR[2] on N8, pool -> oB [N16] ----
  hipMemsetAsync(head, 0xFF, (size_t)N16 * 4, stream);
  k_fill<<<(N8 + 255) / 256, 256, 0, stream>>>(inv16, head, nxt, N8);
  k_encR<<<(N8 + 255) / 256, 256, 0, stream>>>(oA, eRW1 + 2 * 2048, eRb1 + 2 * 32,
                                               fold + 64 + 2 * 64, eRW2 + 2 * 2048,
                                               eRb2 + 2 * 64, s4, N8);
  k_gmax<<<((size_t)N16 * 64 + 255) / 256, 256, 0, stream>>>(s4, head, nxt, oB, N16);

  // ---- level 5: encR[3] on N16 ----
  k_encR<<<(N16 + 255) / 256, 256, 0, stream>>>(oB, eRW1 + 3 * 2048, eRb1 + 3 * 32,
                                                fold + 64 + 3 * 64, eRW2 + 3 * 2048,
                                                eRb2 + 3 * 64, s5, N16);

  // ---- decoders (in place, top-down) ----
  k_dec<<<(N16 + 255) / 256, 256, 0, stream>>>(s5, s5, nullptr, mlpW + 0 * 4096, mlpb + 0 * 64,
                                               decW + 0 * 8192, decb + 0 * 64,
                                               fold + 320 + 0 * 128, N16);
  k_dec<<<(N8 + 255) / 256, 256, 0, stream>>>(s4, s5, inv16, mlpW + 1 * 4096, mlpb + 1 * 64,
                                              decW + 1 * 8192, decb + 1 * 64,
                                              fold + 320 + 1 * 128, N8);
  k_dec<<<(N4 + 255) / 256, 256, 0, stream>>>(s3, s4, inv8, mlpW + 2 * 4096, mlpb + 2 * 64,
                                              decW + 2 * 8192, decb + 2 * 64,
                                              fold + 320 + 2 * 128, N4);
  k_dec<<<(N2 + 255) / 256, 256, 0, stream>>>(s2, s3, inv4, mlpW + 3 * 4096, mlpb + 3 * 64,
                                              decW + 3 * 8192, decb + 3 * 64,
                                              fold + 320 + 3 * 128, N2);
  k_dec<<<(N1 + 255) / 256, 256, 0, stream>>>(s1, s2, inv2, mlpW + 4 * 4096, mlpb + 4 * 64,
                                              decW + 4 * 8192, decb + 4 * 64,
                                              fold + 320 + 4 * 128, N1);
}

// Round 4
// 2295.246 us; speedup vs baseline: 4.4013x; 1.0151x over previous
//
#include <hip/hip_runtime.h>

#define N1 1000000
#define N2 400000
#define N4 150000
#define N8 60000
#define N16 20000

constexpr float BN_EPS = 1e-5f;

__device__ __forceinline__ float lrelu(float x) { return fmaxf(x, 0.1f * x); }

// Fold all BatchNorm params into scale/shift once per call.
// fold: enc0 sc[32],sh[32] @0; encR b: sc[32],sh[32] @64+b*64; dec i: sc[64],sh[64] @320+i*128.
__global__ void k_fold(const float* g0, const float* be0, const float* m0, const float* v0,
                       const float* gR, const float* beR, const float* mR, const float* vR,
                       const float* gD, const float* beD, const float* mD, const float* vD,
                       float* fold) {
  int t = threadIdx.x;
  if (t < 32) {
    float sc = g0[t] * rsqrtf(v0[t] + BN_EPS);
    fold[t] = sc;
    fold[32 + t] = be0[t] - m0[t] * sc;
  }
  if (t < 128) {
    int b = t >> 5, c = t & 31;
    float sc = gR[b * 32 + c] * rsqrtf(vR[b * 32 + c] + BN_EPS);
    fold[64 + b * 64 + c] = sc;
    fold[64 + b * 64 + 32 + c] = beR[b * 32 + c] - mR[b * 32 + c] * sc;
  }
  for (int i = t; i < 320; i += blockDim.x) {
    int b = i >> 6, c = i & 63;
    float sc = gD[b * 64 + c] * rsqrtf(vD[b * 64 + c] + BN_EPS);
    fold[320 + b * 128 + c] = sc;
    fold[320 + b * 128 + 64 + c] = beD[b * 64 + c] - mD[b * 64 + c] * sc;
  }
}

// Build per-segment linked lists. head pre-set to -1. One 4B atomic per row.
__global__ __launch_bounds__(256) void k_fill(const int* __restrict__ idx,
                                              int* head, int* nxt, int n) {
  int i = blockIdx.x * 256 + threadIdx.x;
  if (i < n) nxt[i] = atomicExch(&head[idx[i]], i);
}

// Segment max by chained gather: one wave per segment, one thread per channel.
__global__ __launch_bounds__(256) void k_gmax(
    const float* __restrict__ src, const int* __restrict__ head,
    const int* __restrict__ nxt, float* __restrict__ dst, int nseg) {
  int t = blockIdx.x * 256 + threadIdx.x;
  int seg = t >> 6, ch = t & 63;
  if (seg >= nseg) return;
  float m = -INFINITY;
  for (int p = head[seg]; p >= 0; p = nxt[p])
    m = fmaxf(m, src[(size_t)p * 64 + ch]);
  dst[(size_t)seg * 64 + ch] = (m == -INFINITY) ? 0.0f : m;
}

// encoder block 0: x[9] -> h[32] -> out[64].
// h computed in chunks of 8; only acc[64]+hq[8]+xr[9] live. Runtime loops touch
// only addresses; register arrays indexed solely in small static regions.
__global__ __launch_bounds__(256, 3) void k_enc0(
    const float* __restrict__ x,
    const float* __restrict__ W1, const float* __restrict__ b1,
    const float* __restrict__ fold,
    const float* __restrict__ W2, const float* __restrict__ b2,
    float* __restrict__ out, int n) {
  int row = blockIdx.x * 256 + threadIdx.x;
  if (row >= n) return;

  float xr[9];
  const float* xp = x + (size_t)row * 9;
#pragma unroll
  for (int k = 0; k < 9; ++k) xr[k] = xp[k];

  float acc[64];
#pragma unroll
  for (int j = 0; j < 64; ++j) acc[j] = b2[j];

  for (int c = 0; c < 4; ++c) {  // runtime loop: c only in addresses
    float hq[8];
#pragma unroll
    for (int j = 0; j < 8; ++j) hq[j] = b1[c * 8 + j];
#pragma unroll
    for (int k = 0; k < 9; ++k) {
#pragma unroll
      for (int j = 0; j < 8; ++j) hq[j] = fmaf(xr[k], W1[k * 32 + c * 8 + j], hq[j]);
    }
#pragma unroll
    for (int j = 0; j < 8; ++j)
      hq[j] = lrelu(hq[j]) * fold[c * 8 + j] + fold[32 + c * 8 + j];
#pragma unroll
    for (int k2 = 0; k2 < 8; ++k2) {
      float hv = hq[k2];
#pragma unroll
      for (int j = 0; j < 64; ++j)
        acc[j] = fmaf(hv, W2[(c * 8 + k2) * 64 + j], acc[j]);
    }
  }

  float4* opv = (float4*)(out + (size_t)row * 64);
  for (int k = 0; k < 16; ++k) {
    float4 t;
    t.x = lrelu(acc[4 * k + 0]); t.y = lrelu(acc[4 * k + 1]);
    t.z = lrelu(acc[4 * k + 2]); t.w = lrelu(acc[4 * k + 3]);
    opv[k] = t;
  }
}

// encoder blocks 1..4: in[64] -> h[32] -> out[64]. Input streamed from global
// (float4) once per h-chunk (4x re-read, L1/L2-resident). Live: acc64+hq8.
__global__ __launch_bounds__(256, 3) void k_encR(
    const float* __restrict__ xin,
    const float* __restrict__ W1, const float* __restrict__ b1,
    const float* __restrict__ fold,
    const float* __restrict__ W2, const float* __restrict__ b2,
    float* __restrict__ out, int n) {
  int row = blockIdx.x * 256 + threadIdx.x;
  if (row >= n) return;
  const float4* xp = (const float4*)(xin + (size_t)row * 64);

  float acc[64];
#pragma unroll
  for (int j = 0; j < 64; ++j) acc[j] = b2[j];

  for (int c = 0; c < 4; ++c) {
    float hq[8];
#pragma unroll
    for (int j = 0; j < 8; ++j) hq[j] = b1[c * 8 + j];
    for (int k4 = 0; k4 < 16; ++k4) {
      float4 v = xp[k4];
#pragma unroll
      for (int j = 0; j < 8; ++j) {
        hq[j] = fmaf(v.x, W1[(k4 * 4 + 0) * 32 + c * 8 + j], hq[j]);
        hq[j] = fmaf(v.y, W1[(k4 * 4 + 1) * 32 + c * 8 + j], hq[j]);
        hq[j] = fmaf(v.z, W1[(k4 * 4 + 2) * 32 + c * 8 + j], hq[j]);
        hq[j] = fmaf(v.w, W1[(k4 * 4 + 3) * 32 + c * 8 + j], hq[j]);
      }
    }
#pragma unroll
    for (int j = 0; j < 8; ++j)
      hq[j] = lrelu(hq[j]) * fold[c * 8 + j] + fold[32 + c * 8 + j];
#pragma unroll
    for (int k2 = 0; k2 < 8; ++k2) {
      float hv = hq[k2];
#pragma unroll
      for (int j = 0; j < 64; ++j)
        acc[j] = fmaf(hv, W2[(c * 8 + k2) * 64 + j], acc[j]);
    }
  }

  float4* opv = (float4*)(out + (size_t)row * 64);
  for (int k = 0; k < 16; ++k) {
    float4 t;
    t.x = lrelu(acc[4 * k + 0]); t.y = lrelu(acc[4 * k + 1]);
    t.z = lrelu(acc[4 * k + 2]); t.w = lrelu(acc[4 * k + 3]);
    opv[k] = t;
  }
}

// decoder block, in place. Only out[64] (+sk[8]) live; last and cur streamed
// from global. Runtime loops carry addresses only.
__global__ __launch_bounds__(256, 3) void k_dec(
    float* inout, const float* __restrict__ lastbuf, const int* __restrict__ idx,
    const float* __restrict__ mlpW, const float* __restrict__ mlpb,
    const float* __restrict__ decW, const float* __restrict__ decb,
    const float* __restrict__ fold, int n) {
  int row = blockIdx.x * 256 + threadIdx.x;
  if (row >= n) return;
  int lrow = idx ? idx[row] : row;

  float out[64];
#pragma unroll
  for (int j = 0; j < 64; ++j) out[j] = decb[j];

  // ---- last contribution: decW rows 64..127, streamed ----
  const float4* lp = (const float4*)(lastbuf + (size_t)lrow * 64);
  for (int k4 = 0; k4 < 16; ++k4) {
    float4 lv = lp[k4];
#pragma unroll
    for (int j = 0; j < 64; ++j) {
      out[j] = fmaf(lv.x, decW[(64 + k4 * 4 + 0) * 64 + j], out[j]);
      out[j] = fmaf(lv.y, decW[(64 + k4 * 4 + 1) * 64 + j], out[j]);
      out[j] = fmaf(lv.z, decW[(64 + k4 * 4 + 2) * 64 + j], out[j]);
      out[j] = fmaf(lv.w, decW[(64 + k4 * 4 + 3) * 64 + j], out[j]);
    }
  }

  // ---- skip MLP in 8-ch chunks; cur streamed per chunk (L1/L2 hot) ----
  const float4* cp = (const float4*)(inout + (size_t)row * 64);
  for (int c = 0; c < 8; ++c) {
    float sk[8];
#pragma unroll
    for (int j = 0; j < 8; ++j) sk[j] = mlpb[c * 8 + j];
    for (int k4 = 0; k4 < 16; ++k4) {
      float4 cv = cp[k4];
#pragma unroll
      for (int j = 0; j < 8; ++j) {
        sk[j] = fmaf(cv.x, mlpW[(k4 * 4 + 0) * 64 + c * 8 + j], sk[j]);
        sk[j] = fmaf(cv.y, mlpW[(k4 * 4 + 1) * 64 + c * 8 + j], sk[j]);
        sk[j] = fmaf(cv.z, mlpW[(k4 * 4 + 2) * 64 + c * 8 + j], sk[j]);
        sk[j] = fmaf(cv.w, mlpW[(k4 * 4 + 3) * 64 + c * 8 + j], sk[j]);
      }
    }
#pragma unroll
    for (int j = 0; j < 8; ++j) sk[j] = lrelu(sk[j]);
#pragma unroll
    for (int k2 = 0; k2 < 8; ++k2) {
      float sv = sk[k2];
#pragma unroll
      for (int j = 0; j < 64; ++j)
        out[j] = fmaf(sv, decW[(c * 8 + k2) * 64 + j], out[j]);
    }
  }

  float4* opv = (float4*)(inout + (size_t)row * 64);
  for (int k = 0; k < 16; ++k) {
    float4 t;
    t.x = lrelu(out[4 * k + 0] * fold[4 * k + 0] + fold[64 + 4 * k + 0]);
    t.y = lrelu(out[4 * k + 1] * fold[4 * k + 1] + fold[64 + 4 * k + 1]);
    t.z = lrelu(out[4 * k + 2] * fold[4 * k + 2] + fold[64 + 4 * k + 2]);
    t.w = lrelu(out[4 * k + 3] * fold[4 * k + 3] + fold[64 + 4 * k + 3]);
    opv[k] = t;
  }
}

extern "C" void kernel_launch(void* const* d_in, const int* in_sizes, int n_in,
                              void* d_out, int out_size, void* d_ws, size_t ws_size,
                              hipStream_t stream) {
  const float* pt   = (const float*)d_in[0];
  const int* inv2   = (const int*)d_in[1];
  const int* inv4   = (const int*)d_in[2];
  const int* inv8   = (const int*)d_in[3];
  const int* inv16  = (const int*)d_in[4];
  const float* e0W1 = (const float*)d_in[5];
  const float* e0b1 = (const float*)d_in[6];
  const float* e0g  = (const float*)d_in[7];
  const float* e0be = (const float*)d_in[8];
  const float* e0m  = (const float*)d_in[9];
  const float* e0v  = (const float*)d_in[10];
  const float* e0W2 = (const float*)d_in[11];
  const float* e0b2 = (const float*)d_in[12];
  const float* eRW1 = (const float*)d_in[13];
  const float* eRb1 = (const float*)d_in[14];
  const float* eRg  = (const float*)d_in[15];
  const float* eRbe = (const float*)d_in[16];
  const float* eRm  = (const float*)d_in[17];
  const float* eRv  = (const float*)d_in[18];
  const float* eRW2 = (const float*)d_in[19];
  const float* eRb2 = (const float*)d_in[20];
  const float* mlpW = (const float*)d_in[21];
  const float* mlpb = (const float*)d_in[22];
  const float* decW = (const float*)d_in[23];
  const float* decb = (const float*)d_in[24];
  const float* decg = (const float*)d_in[25];
  const float* decbe= (const float*)d_in[26];
  const float* decm = (const float*)d_in[27];
  const float* decv = (const float*)d_in[28];

  float* s1 = (float*)d_out;
  float* s2 = s1 + (size_t)N1 * 64;
  float* s3 = s2 + (size_t)N2 * 64;
  float* s4 = s3 + (size_t)N4 * 64;
  float* s5 = s4 + (size_t)N8 * 64;

  // workspace: fold | oA (N2*64 f) | oB (N4*64 f) | head (N2 i) | nxt (N1 i)
  float* fold = (float*)d_ws;
  float* oA   = fold + 1024;
  float* oB   = oA + (size_t)N2 * 64;
  int* head   = (int*)(oB + (size_t)N4 * 64);
  int* nxt    = head + N2;

  k_fold<<<1, 320, 0, stream>>>(e0g, e0be, e0m, e0v, eRg, eRbe, eRm, eRv,
                                decg, decbe, decm, decv, fold);

  // ---- level 1: enc0 on N1, pool -> oA [N2] ----
  hipMemsetAsync(head, 0xFF, (size_t)N2 * 4, stream);
  k_fill<<<(N1 + 255) / 256, 256, 0, stream>>>(inv2, head, nxt, N1);
  k_enc0<<<(N1 + 255) / 256, 256, 0, stream>>>(pt, e0W1, e0b1, fold, e0W2, e0b2, s1, N1);
  k_gmax<<<((size_t)N2 * 64 + 255) / 256, 256, 0, stream>>>(s1, head, nxt, oA, N2);

  // ---- level 2: encR[0] on N2, pool -> oB [N4] ----
  hipMemsetAsync(head, 0xFF, (size_t)N4 * 4, stream);
  k_fill<<<(N2 + 255) / 256, 256, 0, stream>>>(inv4, head, nxt, N2);
  k_encR<<<(N2 + 255) / 256, 256, 0, stream>>>(oA, eRW1 + 0 * 2048, eRb1 + 0 * 32,
                                               fold + 64 + 0 * 64, eRW2 + 0 * 2048,
                                               eRb2 + 0 * 64, s2, N2);
  k_gmax<<<((size_t)N4 * 64 + 255) / 256, 256, 0, stream>>>(s2, head, nxt, oB, N4);

  // ---- level 3: encR[1] on N4, pool -> oA [N8] ----
  hipMemsetAsync(head, 0xFF, (size_t)N8 * 4, stream);
  k_fill<<<(N4 + 255) / 256, 256, 0, stream>>>(inv8, head, nxt, N4);
  k_encR<<<(N4 + 255) / 256, 256, 0, stream>>>(oB, eRW1 + 1 * 2048, eRb1 + 1 * 32,
                                               fold + 64 + 1 * 64, eRW2 + 1 * 2048,
                                               eRb2 + 1 * 64, s3, N4);
  k_gmax<<<((size_t)N8 * 64 + 255) / 256, 256, 0, stream>>>(s3, head, nxt, oA, N8);

  // ---- level 4: encR[2] on N8, pool -> oB [N16] ----
  hipMemsetAsync(head, 0xFF, (size_t)N16 * 4, stream);
  k_fill<<<(N8 + 255) / 256, 256, 0, stream>>>(inv16, head, nxt, N8);
  k_encR<<<(N8 + 255) / 256, 256, 0, stream>>>(oA, eRW1 + 2 * 2048, eRb1 + 2 * 32,
                                               fold + 64 + 2 * 64, eRW2 + 2 * 2048,
                                               eRb2 + 2 * 64, s4, N8);
  k_gmax<<<((size_t)N16 * 64 + 255) / 256, 256, 0, stream>>>(s4, head, nxt, oB, N16);

  // ---- level 5: encR[3] on N16 ----
  k_encR<<<(N16 + 255) / 256, 256, 0, stream>>>(oB, eRW1 + 3 * 2048, eRb1 + 3 * 32,
                                                fold + 64 + 3 * 64, eRW2 + 3 * 2048,
                                                eRb2 + 3 * 64, s5, N16);

  // ---- decoders (in place, top-down) ----
  k_dec<<<(N16 + 255) / 256, 256, 0, stream>>>(s5, s5, nullptr, mlpW + 0 * 4096, mlpb + 0 * 64,
                                               decW + 0 * 8192, decb + 0 * 64,
                                               fold + 320 + 0 * 128, N16);
  k_dec<<<(N8 + 255) / 256, 256, 0, stream>>>(s4, s5, inv16, mlpW + 1 * 4096, mlpb + 1 * 64,
                                              decW + 1 * 8192, decb + 1 * 64,
                                              fold + 320 + 1 * 128, N8);
  k_dec<<<(N4 + 255) / 256, 256, 0, stream>>>(s3, s4, inv8, mlpW + 2 * 4096, mlpb + 2 * 64,
                                              decW + 2 * 8192, decb + 2 * 64,
                                              fold + 320 + 2 * 128, N4);
  k_dec<<<(N2 + 255) / 256, 256, 0, stream>>>(s2, s3, inv4, mlpW + 3 * 4096, mlpb + 3 * 64,
                                              decW + 3 * 8192, decb + 3 * 64,
                                              fold + 320 + 3 * 128, N2);
  k_dec<<<(N1 + 255) / 256, 256, 0, stream>>>(s1, s2, inv2, mlpW + 4 * 4096, mlpb + 4 * 64,
                                              decW + 4 * 8192, decb + 4 * 64,
                                              fold + 320 + 4 * 128, N1);
}